// Round 3
// baseline (842.347 us; speedup 1.0000x reference)
//
#include <hip/hip_runtime.h>
#include <stdint.h>

typedef uint16_t u16;
typedef __bf16 bf16x8 __attribute__((ext_vector_type(8)));
typedef float f32x4 __attribute__((ext_vector_type(4)));

#define EPS 1e-3f
#define SCALE_F 0.07216878364870323f /* 192^-0.5 */

__device__ __forceinline__ float bf2f(u16 u) {
    union { uint32_t i; float f; } v; v.i = ((uint32_t)u) << 16; return v.f;
}
__device__ __forceinline__ u16 f2bf(float f) {
    union { float f; uint32_t i; } v; v.f = f;
    uint32_t x = v.i;
    return (u16)((x + 0x7fffu + ((x >> 16) & 1u)) >> 16);
}

__device__ __forceinline__ void async_cp16(const u16* g, u16* l) {
    __builtin_amdgcn_global_load_lds(
        (const __attribute__((address_space(1))) uint32_t*)g,
        (__attribute__((address_space(3))) uint32_t*)l,
        16, 0, 0);
}

// ---------------------------------------------------------------------------
// dtype-adaptive input conversion: all 14 float tensors -> bf16 arena.
// fp32 detected via q_norm_w[0] bit pattern (all-ones tensor).
// ---------------------------------------------------------------------------
struct Cvt {
    const void* src[14];
    u16* dst[14];
    long off[15];
};

__global__ __launch_bounds__(256) void cvt_kernel(Cvt c, const uint32_t* qnw_u32, long total8)
{
    const long i8 = (long)blockIdx.x * 256 + threadIdx.x;
    if (i8 >= total8) return;
    const long e = i8 * 8;
    const bool is_f32 = (qnw_u32[0] == 0x3F800000u);
    int t = 0;
    while (e >= c.off[t + 1]) ++t;          // all segment sizes are multiples of 8
    const long local = e - c.off[t];
    u16* d = c.dst[t] + local;
    if (is_f32) {
        const float* s = (const float*)c.src[t] + local;
        #pragma unroll
        for (int j = 0; j < 8; ++j) d[j] = f2bf(s[j]);
    } else {
        const u16* s = (const u16*)c.src[t] + local;
        #pragma unroll
        for (int j = 0; j < 8; ++j) d[j] = s[j];
    }
}

// ---------------------------------------------------------------------------
// Generic bf16 GEMM: C[M,N] = rnd(rnd(alpha*acc) + bias), acc = A[M,K]@B[N,K]^T
// z-batched: zg = z0 + blockIdx.z; zb = zg/hcnt; zh = zg%hcnt
// per-operand offset = zl*sXl + zb*sXb + zh*sXh (elements)
// B rows clamped to N-1 (safe staging when N%128!=0); stores guarded col<N.
// M%128==0, K%32==0 required. c_f32: store fp32 (only valid with C strides 0).
// ---------------------------------------------------------------------------
__global__ __launch_bounds__(256) void gemm_bt_kernel(
    const u16* __restrict__ A, const u16* __restrict__ B,
    const u16* __restrict__ bias, u16* __restrict__ C,
    int M, int N, int K, int lda, int ldb, int ldc, float alpha, int c_f32,
    int z0, int hcnt,
    long sAl, long sAb, long sAh,
    long sBl, long sBb, long sBh,
    long sCl, long sCb, long sCh)
{
    const int zl = blockIdx.z;
    const int zg = z0 + zl;
    const int zb = zg / hcnt, zh = zg - zb * hcnt;
    A += (long)zl * sAl + (long)zb * sAb + (long)zh * sAh;
    B += (long)zl * sBl + (long)zb * sBb + (long)zh * sBh;
    C += (long)zl * sCl + (long)zb * sCb + (long)zh * sCh;

    __shared__ u16 As[128 * 32];
    __shared__ u16 Bs[128 * 32];

    const int tid  = threadIdx.x;
    const int wave = tid >> 6, lane = tid & 63;
    const int wm = (wave >> 1) << 6, wn = (wave & 1) << 6;
    const int quad = lane >> 4, r15 = lane & 15;

    const int tileM = blockIdx.y * 128;
    const int tileN = blockIdx.x * 128;

    const int c0 = tid, c1 = tid + 256;
    const int rA0 = c0 >> 2, kb0 = (c0 & 3) << 3;
    const int rA1 = c1 >> 2, kb1 = (c1 & 3) << 3;
    int rB0 = tileN + rA0; if (rB0 > N - 1) rB0 = N - 1;
    int rB1 = tileN + rA1; if (rB1 > N - 1) rB1 = N - 1;

    const u16* Ag0 = A + (long)(tileM + rA0) * lda + kb0;
    const u16* Ag1 = A + (long)(tileM + rA1) * lda + kb1;
    const u16* Bg0 = B + (long)rB0 * ldb + kb0;
    const u16* Bg1 = B + (long)rB1 * ldb + kb1;
    u16* lA0 = &As[c0 << 3];
    u16* lA1 = &As[c1 << 3];
    u16* lB0 = &Bs[c0 << 3];
    u16* lB1 = &Bs[c1 << 3];

    f32x4 acc[4][4] = {};

    const u16* aRd[4]; const u16* bRd[4];
    #pragma unroll
    for (int i = 0; i < 4; ++i) {
        aRd[i] = &As[(wm + i * 16 + r15) * 32 + quad * 8];
        bRd[i] = &Bs[(wn + i * 16 + r15) * 32 + quad * 8];
    }

    for (int k0 = 0; k0 < K; k0 += 32) {
        async_cp16(Ag0, lA0);
        async_cp16(Ag1, lA1);
        async_cp16(Bg0, lB0);
        async_cp16(Bg1, lB1);
        Ag0 += 32; Ag1 += 32; Bg0 += 32; Bg1 += 32;
        __syncthreads();
        bf16x8 af[4], bfr[4];
        #pragma unroll
        for (int i = 0; i < 4; ++i) {
            af[i]  = *(const bf16x8*)aRd[i];
            bfr[i] = *(const bf16x8*)bRd[i];
        }
        #pragma unroll
        for (int mi = 0; mi < 4; ++mi)
            #pragma unroll
            for (int ni = 0; ni < 4; ++ni)
                acc[mi][ni] = __builtin_amdgcn_mfma_f32_16x16x32_bf16(
                    af[mi], bfr[ni], acc[mi][ni], 0, 0, 0);
        __syncthreads();
    }

    // D[m=quad*4+r][n=r15]
    #pragma unroll
    for (int mi = 0; mi < 4; ++mi) {
        const int row = tileM + wm + mi * 16 + quad * 4;
        #pragma unroll
        for (int ni = 0; ni < 4; ++ni) {
            const int col = tileN + wn + ni * 16 + r15;
            if (col < N) {
                if (c_f32) {
                    const float bv = bias ? bf2f(bias[col]) : 0.f;
                    #pragma unroll
                    for (int r = 0; r < 4; ++r)
                        ((float*)C)[(long)(row + r) * ldc + col] =
                            acc[mi][ni][r] * alpha + bv;
                } else {
                    #pragma unroll
                    for (int r = 0; r < 4; ++r) {
                        u16 t = f2bf(acc[mi][ni][r] * alpha);
                        if (bias) t = f2bf(bf2f(t) + bf2f(bias[col]));
                        C[(long)(row + r) * ldc + col] = t;
                    }
                }
            }
        }
    }
}

// ---------------------------------------------------------------------------
__global__ __launch_bounds__(256) void rmsnorm_kernel(
    const u16* __restrict__ x, const u16* __restrict__ w, u16* __restrict__ y, int n)
{
    const long row = blockIdx.x;
    const u16* xr = x + row * n;
    u16* yr = y + row * n;
    const int tid = threadIdx.x;
    const int cnt = n >> 8;
    float v[4];
    float ss = 0.f;
    for (int i = 0; i < cnt; ++i) { v[i] = bf2f(xr[tid + (i << 8)]); ss += v[i] * v[i]; }
    for (int o = 32; o; o >>= 1) ss += __shfl_xor(ss, o, 64);
    __shared__ float sm[4];
    if ((tid & 63) == 0) sm[tid >> 6] = ss;
    __syncthreads();
    const float rinv = rsqrtf((sm[0] + sm[1] + sm[2] + sm[3]) / (float)n + EPS);
    for (int i = 0; i < cnt; ++i) {
        const u16 nb = f2bf(v[i] * rinv);
        yr[tid + (i << 8)] = f2bf(bf2f(w[tid + (i << 8)]) * bf2f(nb));
    }
}

// kvf row (576) in place: rmsnorm(cols 0..511, w) ; rope(cols 512..575)
__global__ __launch_bounds__(256) void kv_kernel(
    const u16* __restrict__ cosb, const u16* __restrict__ sinb,
    const u16* __restrict__ w, u16* __restrict__ kvf)
{
    const long bs = blockIdx.x;
    const int s = (int)(bs & 2047);
    u16* io = kvf + bs * 576;
    const int tid = threadIdx.x;
    const float v0 = bf2f(io[tid * 2]), v1 = bf2f(io[tid * 2 + 1]);
    float ss = v0 * v0 + v1 * v1;
    for (int off = 32; off; off >>= 1) ss += __shfl_xor(ss, off, 64);
    __shared__ float sm[4];
    if ((tid & 63) == 0) sm[tid >> 6] = ss;
    __syncthreads();
    const float rinv = rsqrtf((sm[0] + sm[1] + sm[2] + sm[3]) / 512.f + EPS);
    const u16 n0 = f2bf(v0 * rinv), n1 = f2bf(v1 * rinv);
    io[tid * 2]     = f2bf(bf2f(w[tid * 2]) * bf2f(n0));
    io[tid * 2 + 1] = f2bf(bf2f(w[tid * 2 + 1]) * bf2f(n1));
    if (tid < 32) {
        const int j = tid;
        const float xr = bf2f(io[512 + 2 * j]), xi = bf2f(io[512 + 2 * j + 1]);
        const float c = bf2f(cosb[s * 32 + j]), si = bf2f(sinb[s * 32 + j]);
        io[512 + 2 * j]     = f2bf(bf2f(f2bf(xr * c))  - bf2f(f2bf(xi * si)));
        io[512 + 2 * j + 1] = f2bf(bf2f(f2bf(xr * si)) + bf2f(f2bf(xi * c)));
    }
}

// in-place rope on q's pe columns (h*192+128 .. +191), unscaled
__global__ __launch_bounds__(256) void rope_q_kernel(
    const u16* __restrict__ cosb, const u16* __restrict__ sinb, u16* __restrict__ q)
{
    const int idx = blockIdx.x * 256 + threadIdx.x; // 4096*16*32
    const int j = idx & 31;
    const int h = (idx >> 5) & 15;
    const int bs = idx >> 9;
    const int s = bs & 2047;
    u16* p = q + (long)bs * 3072 + h * 192 + 128 + 2 * j;
    const float xr = bf2f(p[0]), xi = bf2f(p[1]);
    const float c = bf2f(cosb[s * 32 + j]), si = bf2f(sinb[s * 32 + j]);
    p[0] = f2bf(bf2f(f2bf(xr * c))  - bf2f(f2bf(xi * si)));
    p[1] = f2bf(bf2f(f2bf(xr * si)) + bf2f(f2bf(xi * c)));
}

// broadcast roped k_pe (kvf cols 512..575) into K2 cols h*192+128..+191
__global__ __launch_bounds__(256) void k2rope_kernel(
    const u16* __restrict__ kvf, u16* __restrict__ K2)
{
    const long row = blockIdx.x;
    const int tid = threadIdx.x;
    #pragma unroll
    for (int i = 0; i < 4; ++i) {
        const int slot = tid + (i << 8);      // 0..1023 = 16h x 64r
        const int h = slot >> 6, r = slot & 63;
        K2[row * 3072 + h * 192 + 128 + r] = kvf[row * 576 + 512 + r];
    }
}

// in-place row softmax over 2048 bf16
__global__ __launch_bounds__(256) void softmax_kernel(u16* __restrict__ sc)
{
    const long row = blockIdx.x;
    u16* p = sc + row * 2048;
    const int tid = threadIdx.x;
    float v[8];
    float m = -1e30f;
    #pragma unroll
    for (int i = 0; i < 8; ++i) { v[i] = bf2f(p[tid + (i << 8)]); m = fmaxf(m, v[i]); }
    for (int o = 32; o; o >>= 1) m = fmaxf(m, __shfl_xor(m, o, 64));
    __shared__ float sm[4];
    if ((tid & 63) == 0) sm[tid >> 6] = m;
    __syncthreads();
    m = fmaxf(fmaxf(sm[0], sm[1]), fmaxf(sm[2], sm[3]));
    __syncthreads();
    float ssum = 0.f;
    #pragma unroll
    for (int i = 0; i < 8; ++i) { v[i] = __expf(v[i] - m); ssum += v[i]; }
    for (int o = 32; o; o >>= 1) ssum += __shfl_xor(ssum, o, 64);
    if ((tid & 63) == 0) sm[tid >> 6] = ssum;
    __syncthreads();
    const float rinv = 1.f / (sm[0] + sm[1] + sm[2] + sm[3]);
    #pragma unroll
    for (int i = 0; i < 8; ++i) p[tid + (i << 8)] = f2bf(v[i] * rinv);
}

// ---------------------------------------------------------------------------
extern "C" void kernel_launch(void* const* d_in, const int* in_sizes, int n_in,
                              void* d_out, int out_size, void* d_ws, size_t ws_size,
                              hipStream_t stream)
{
    float* out = (float*)d_out;   // fp32 output per reference dtype

    // -------- bf16 arena layout in d_ws --------
    char* p = (char*)d_ws;
    auto alloc = [&](size_t elems) { u16* r = (u16*)p; p += elems * 2; return r; };
    // converted inputs (except x, which lives in d_out's lower half)
    u16* c_cos  = alloc(65536);
    u16* c_sin  = alloc(65536);
    u16* c_wqa  = alloc(2097152);
    u16* c_wqab = alloc(1024);
    u16* c_qnw  = alloc(1024);
    u16* c_wqb  = alloc(3145728);
    u16* c_wqbb = alloc(3072);
    u16* c_wkva = alloc(1179648);
    u16* c_wkvab= alloc(576);
    u16* c_kvnw = alloc(512);
    u16* c_wkvb = alloc(2097152);
    u16* c_wo   = alloc(4194304);
    u16* c_wob  = alloc(2048);
    // intermediates
    u16* q   = alloc(4096UL * 3072);          // 25.2 MB
    u16* kvf = alloc(4096UL * 576);           //  4.7 MB
    u16* K2  = alloc(4096UL * 3072);          // 25.2 MB
    u16* O   = alloc(4096UL * 2048);          // 16.8 MB
    u16* q_a = (u16*)p;                       //  8.4 MB (tail)
    u16* scores = (u16*)p;                    //  tail, slices of 8.4 MB
    // d_out scratch: x_bf16 (lower 16.8 MB, dead after step 4),
    //                Vt     (upper 16.8 MB, dead before final GEMM)
    u16* xb = (u16*)d_out;
    u16* Vt = (u16*)d_out + 8388608;

    const size_t used = (size_t)(p - (char*)d_ws);
    const size_t tail = ws_size > used ? ws_size - used : 0;
    long zc = (long)(tail / (2048UL * 2048 * 2));
    if (zc < 1) zc = 1;
    if (zc > 8) zc = 8;

    // -------- conversion kernel --------
    Cvt cv;
    const long sizes[14] = {8388608, 65536, 65536, 2097152, 1024, 1024, 3145728,
                            3072, 1179648, 576, 512, 2097152, 4194304, 2048};
    u16* dsts[14] = {xb, c_cos, c_sin, c_wqa, c_wqab, c_qnw, c_wqb, c_wqbb,
                     c_wkva, c_wkvab, c_kvnw, c_wkvb, c_wo, c_wob};
    const int srcidx[14] = {0, 2, 3, 4, 5, 6, 7, 8, 9, 10, 11, 12, 13, 14};
    long acc_off = 0;
    for (int t = 0; t < 14; ++t) {
        cv.src[t] = d_in[srcidx[t]];
        cv.dst[t] = dsts[t];
        cv.off[t] = acc_off;
        acc_off += sizes[t];
    }
    cv.off[14] = acc_off;
    const long total8 = acc_off / 8;
    cvt_kernel<<<dim3((unsigned)((total8 + 255) / 256)), dim3(256), 0, stream>>>(
        cv, (const uint32_t*)d_in[6], total8);

    auto gemm = [&](const u16* A, const u16* B, const u16* bias, u16* C,
                    int M, int N, int K, int lda, int ldb, int ldc, float alpha,
                    int c_f32, int nz, int z0, int hcnt,
                    long sAl, long sAb, long sAh,
                    long sBl, long sBb, long sBh,
                    long sCl, long sCb, long sCh) {
        dim3 grid((N + 127) / 128, M / 128, nz);
        gemm_bt_kernel<<<grid, dim3(256), 0, stream>>>(
            A, B, bias, C, M, N, K, lda, ldb, ldc, alpha, c_f32, z0, hcnt,
            sAl, sAb, sAh, sBl, sBb, sBh, sCl, sCb, sCh);
    };

    // 1) q_a = x @ wq_a^T + b
    gemm(xb, c_wqa, c_wqab, q_a, 4096, 1024, 2048, 2048, 2048, 1024, 1.f, 0,
         1, 0, 1, 0, 0, 0, 0, 0, 0, 0, 0, 0);
    // 2) rmsnorm in place
    rmsnorm_kernel<<<4096, 256, 0, stream>>>(q_a, c_qnw, q_a, 1024);
    // 3) q = q_a @ wq_b^T + b
    gemm(q_a, c_wqb, c_wqbb, q, 4096, 3072, 1024, 1024, 1024, 3072, 1.f, 0,
         1, 0, 1, 0, 0, 0, 0, 0, 0, 0, 0, 0);
    // 4) kvf = x @ wkv_a^T + b   (last read of xb)
    gemm(xb, c_wkva, c_wkvab, kvf, 4096, 576, 2048, 2048, 2048, 576, 1.f, 0,
         1, 0, 1, 0, 0, 0, 0, 0, 0, 0, 0, 0);
    // 5) kvf in place: norm(0..511) + rope(512..575)
    kv_kernel<<<4096, 256, 0, stream>>>(c_cos, c_sin, c_kvnw, kvf);
    // 6) rope q_pe in place
    rope_q_kernel<<<8192, 256, 0, stream>>>(c_cos, c_sin, q);
    // 7) K2 nope: per head, k_nope[t][d] = kv_c[t] . wkvb[h][d]
    gemm(kvf, c_wkvb, nullptr, K2, 4096, 128, 512, 576, 512, 3072, 1.f, 0,
         16, 0, 16, 0, 0, 0, 0, 0, 256L * 512, 0, 0, 192);
    // 8) K2 rope broadcast
    k2rope_kernel<<<4096, 256, 0, stream>>>(kvf, K2);
    // 9) Vt[b][h][d][t] = wkvb_v[h][d] . kv_c[b][t]  (into d_out upper half)
    gemm(c_wkvb + 128 * 512, kvf, nullptr, Vt, 128, 2048, 512, 512, 576, 2048, 1.f, 0,
         32, 0, 16,
         0, 0, 256L * 512,
         0, 2048L * 576, 0,
         0, 16L * 128 * 2048, 128L * 2048);
    // 10) attention loop over (b,h) chunks
    for (long c0 = 0; c0 < 32; c0 += zc) {
        const int z = (int)((32 - c0) < zc ? (32 - c0) : zc);
        gemm(q, K2, nullptr, scores, 2048, 2048, 192, 3072, 3072, 2048, SCALE_F, 0,
             z, (int)c0, 16,
             0, 2048L * 3072, 192,
             0, 2048L * 3072, 192,
             2048L * 2048, 0, 0);
        softmax_kernel<<<z * 2048, 256, 0, stream>>>(scores);
        gemm(scores, Vt, nullptr, O, 2048, 128, 2048, 2048, 2048, 2048, 1.f, 0,
             z, (int)c0, 16,
             2048L * 2048, 0, 0,
             0, 16L * 128 * 2048, 128L * 2048,
             0, 2048L * 2048, 128);
    }
    // 11) out = O @ wo^T + b  (fp32 store; overwrites all of d_out)
    gemm(O, c_wo, c_wob, (u16*)out, 4096, 2048, 2048, 2048, 2048, 2048, 1.f, 1,
         1, 0, 1, 0, 0, 0, 0, 0, 0, 0, 0, 0);
}

// Round 4
// 797.751 us; speedup vs baseline: 1.0559x; 1.0559x over previous
//
#include <hip/hip_runtime.h>
#include <stdint.h>

typedef uint16_t u16;
typedef __bf16 bf16x8 __attribute__((ext_vector_type(8)));
typedef float f32x4 __attribute__((ext_vector_type(4)));

#define EPS 1e-3f
#define SCALE_F 0.07216878364870323f /* 192^-0.5 */

__device__ __forceinline__ float bf2f(u16 u) {
    union { uint32_t i; float f; } v; v.i = ((uint32_t)u) << 16; return v.f;
}
__device__ __forceinline__ u16 f2bf(float f) {
    union { float f; uint32_t i; } v; v.f = f;
    uint32_t x = v.i;
    return (u16)((x + 0x7fffu + ((x >> 16) & 1u)) >> 16);
}

__device__ __forceinline__ void async_cp16(const u16* g, u16* l) {
    __builtin_amdgcn_global_load_lds(
        (const __attribute__((address_space(1))) uint32_t*)g,
        (__attribute__((address_space(3))) uint32_t*)l,
        16, 0, 0);
}

// ---------------------------------------------------------------------------
// dtype-adaptive input conversion: all 14 float tensors -> bf16 arena.
// fp32 detected via q_norm_w[0] bit pattern (all-ones tensor).
// ---------------------------------------------------------------------------
struct Cvt {
    const void* src[14];
    u16* dst[14];
    long off[15];
};

__global__ __launch_bounds__(256) void cvt_kernel(Cvt c, const uint32_t* qnw_u32, long total8)
{
    const long i8 = (long)blockIdx.x * 256 + threadIdx.x;
    if (i8 >= total8) return;
    const long e = i8 * 8;
    const bool is_f32 = (qnw_u32[0] == 0x3F800000u);
    int t = 0;
    while (e >= c.off[t + 1]) ++t;          // all segment sizes are multiples of 8
    const long local = e - c.off[t];
    u16* d = c.dst[t] + local;
    if (is_f32) {
        const float* s = (const float*)c.src[t] + local;
        #pragma unroll
        for (int j = 0; j < 8; ++j) d[j] = f2bf(s[j]);
    } else {
        const u16* s = (const u16*)c.src[t] + local;
        #pragma unroll
        for (int j = 0; j < 8; ++j) d[j] = s[j];
    }
}

// ---------------------------------------------------------------------------
// Generic bf16 GEMM: C[M,N] = rnd(rnd(alpha*acc) + bias), acc = A[M,K]@B[N,K]^T
// z-batched; B rows clamped; M%128==0, K%32==0. c_f32: fp32 store.
// ---------------------------------------------------------------------------
__global__ __launch_bounds__(256) void gemm_bt_kernel(
    const u16* __restrict__ A, const u16* __restrict__ B,
    const u16* __restrict__ bias, u16* __restrict__ C,
    int M, int N, int K, int lda, int ldb, int ldc, float alpha, int c_f32,
    int z0, int hcnt,
    long sAl, long sAb, long sAh,
    long sBl, long sBb, long sBh,
    long sCl, long sCb, long sCh)
{
    const int zl = blockIdx.z;
    const int zg = z0 + zl;
    const int zb = zg / hcnt, zh = zg - zb * hcnt;
    A += (long)zl * sAl + (long)zb * sAb + (long)zh * sAh;
    B += (long)zl * sBl + (long)zb * sBb + (long)zh * sBh;
    C += (long)zl * sCl + (long)zb * sCb + (long)zh * sCh;

    __shared__ u16 As[128 * 32];
    __shared__ u16 Bs[128 * 32];

    const int tid  = threadIdx.x;
    const int wave = tid >> 6, lane = tid & 63;
    const int wm = (wave >> 1) << 6, wn = (wave & 1) << 6;
    const int quad = lane >> 4, r15 = lane & 15;

    const int tileM = blockIdx.y * 128;
    const int tileN = blockIdx.x * 128;

    const int c0 = tid, c1 = tid + 256;
    const int rA0 = c0 >> 2, kb0 = (c0 & 3) << 3;
    const int rA1 = c1 >> 2, kb1 = (c1 & 3) << 3;
    int rB0 = tileN + rA0; if (rB0 > N - 1) rB0 = N - 1;
    int rB1 = tileN + rA1; if (rB1 > N - 1) rB1 = N - 1;

    const u16* Ag0 = A + (long)(tileM + rA0) * lda + kb0;
    const u16* Ag1 = A + (long)(tileM + rA1) * lda + kb1;
    const u16* Bg0 = B + (long)rB0 * ldb + kb0;
    const u16* Bg1 = B + (long)rB1 * ldb + kb1;
    u16* lA0 = &As[c0 << 3];
    u16* lA1 = &As[c1 << 3];
    u16* lB0 = &Bs[c0 << 3];
    u16* lB1 = &Bs[c1 << 3];

    f32x4 acc[4][4] = {};

    const u16* aRd[4]; const u16* bRd[4];
    #pragma unroll
    for (int i = 0; i < 4; ++i) {
        aRd[i] = &As[(wm + i * 16 + r15) * 32 + quad * 8];
        bRd[i] = &Bs[(wn + i * 16 + r15) * 32 + quad * 8];
    }

    for (int k0 = 0; k0 < K; k0 += 32) {
        async_cp16(Ag0, lA0);
        async_cp16(Ag1, lA1);
        async_cp16(Bg0, lB0);
        async_cp16(Bg1, lB1);
        Ag0 += 32; Ag1 += 32; Bg0 += 32; Bg1 += 32;
        __syncthreads();
        bf16x8 af[4], bfr[4];
        #pragma unroll
        for (int i = 0; i < 4; ++i) {
            af[i]  = *(const bf16x8*)aRd[i];
            bfr[i] = *(const bf16x8*)bRd[i];
        }
        #pragma unroll
        for (int mi = 0; mi < 4; ++mi)
            #pragma unroll
            for (int ni = 0; ni < 4; ++ni)
                acc[mi][ni] = __builtin_amdgcn_mfma_f32_16x16x32_bf16(
                    af[mi], bfr[ni], acc[mi][ni], 0, 0, 0);
        __syncthreads();
    }

    #pragma unroll
    for (int mi = 0; mi < 4; ++mi) {
        const int row = tileM + wm + mi * 16 + quad * 4;
        #pragma unroll
        for (int ni = 0; ni < 4; ++ni) {
            const int col = tileN + wn + ni * 16 + r15;
            if (col < N) {
                if (c_f32) {
                    const float bv = bias ? bf2f(bias[col]) : 0.f;
                    #pragma unroll
                    for (int r = 0; r < 4; ++r)
                        ((float*)C)[(long)(row + r) * ldc + col] =
                            acc[mi][ni][r] * alpha + bv;
                } else {
                    #pragma unroll
                    for (int r = 0; r < 4; ++r) {
                        u16 t = f2bf(acc[mi][ni][r] * alpha);
                        if (bias) t = f2bf(bf2f(t) + bf2f(bias[col]));
                        C[(long)(row + r) * ldc + col] = t;
                    }
                }
            }
        }
    }
}

// ---------------------------------------------------------------------------
// Flash attention: one block = 128 q-rows x one (b,h); loops 16 KV tiles of
// 128. S=Q K2^T (K=192), online softmax (fp32 stats), P (bf16) -> LDS,
// O += P V (Vt is [bh][d][t]). O stored bf16 [bs][h*128+d].
// ---------------------------------------------------------------------------
#define PS_STRIDE 136

__global__ __launch_bounds__(256) void flash_kernel(
    const u16* __restrict__ q, const u16* __restrict__ K2,
    const u16* __restrict__ Vt, u16* __restrict__ O)
{
    __shared__ u16 stage[2][4096];            // 2 x 8KB staging (K / V chunks)
    __shared__ u16 Ps[128 * PS_STRIDE];       // P tile, padded stride
    __shared__ float redA[2][128];            // cross-wave row-max
    __shared__ float redB[2][128];            // cross-wave row-sum

    const int mt = blockIdx.x, bh = blockIdx.y;
    const int b = bh >> 4, h = bh & 15;
    const int tid = threadIdx.x;
    const int wave = tid >> 6, lane = tid & 63;
    const int wm = (wave >> 1) << 6, wn = (wave & 1) << 6;
    const int quad = lane >> 4, r15 = lane & 15;
    const int wi = wave & 1;

    const long qrow0 = (long)b * 2048 + mt * 128;

    // preload Q fragments: [mi][kst], A-layout rows wm+mi*16+r15
    bf16x8 qf[4][6];
    #pragma unroll
    for (int mi = 0; mi < 4; ++mi) {
        const u16* qp = q + (qrow0 + wm + mi * 16 + r15) * 3072 + h * 192 + quad * 8;
        #pragma unroll
        for (int kst = 0; kst < 6; ++kst)
            qf[mi][kst] = *(const bf16x8*)(qp + kst * 32);
    }

    f32x4 Oacc[4][4] = {};
    float m_i[4][4], l_i[4][4];
    #pragma unroll
    for (int mi = 0; mi < 4; ++mi)
        #pragma unroll
        for (int r = 0; r < 4; ++r) { m_i[mi][r] = -1e30f; l_i[mi][r] = 0.f; }

    const int sr0 = tid >> 2,          sc0 = (tid & 3) << 3;
    const int sr1 = (tid + 256) >> 2,  sc1 = ((tid + 256) & 3) << 3;

    const u16* Kbh = K2 + ((long)b * 2048) * 3072 + h * 192;
    const u16* Vbh = Vt + ((long)bh * 128) * 2048;

    for (int j = 0; j < 16; ++j) {
        const u16* Kt    = Kbh + (long)j * 128 * 3072;
        const u16* Vtile = Vbh + j * 128;

        // ---- S = Q K^T over 6 k-chunks of 32 ----
        f32x4 S[4][4] = {};
        #pragma unroll
        for (int kst = 0; kst < 6; ++kst) {
            u16* buf = stage[kst & 1];
            async_cp16(Kt + (long)sr0 * 3072 + kst * 32 + sc0, buf + tid * 8);
            async_cp16(Kt + (long)sr1 * 3072 + kst * 32 + sc1, buf + (tid + 256) * 8);
            __syncthreads();
            bf16x8 bfr[4];
            #pragma unroll
            for (int ni = 0; ni < 4; ++ni)
                bfr[ni] = *(const bf16x8*)&buf[(wn + ni * 16 + r15) * 32 + quad * 8];
            #pragma unroll
            for (int mi = 0; mi < 4; ++mi)
                #pragma unroll
                for (int ni = 0; ni < 4; ++ni)
                    S[mi][ni] = __builtin_amdgcn_mfma_f32_16x16x32_bf16(
                        qf[mi][kst], bfr[ni], S[mi][ni], 0, 0, 0);
        }

        // ---- scale + row-max partials (C layout: row=wm+mi*16+quad*4+r) ----
        #pragma unroll
        for (int mi = 0; mi < 4; ++mi)
            #pragma unroll
            for (int ni = 0; ni < 4; ++ni)
                #pragma unroll
                for (int r = 0; r < 4; ++r)
                    S[mi][ni][r] *= SCALE_F;
        #pragma unroll
        for (int mi = 0; mi < 4; ++mi)
            #pragma unroll
            for (int r = 0; r < 4; ++r) {
                float t = fmaxf(fmaxf(S[mi][0][r], S[mi][1][r]),
                                fmaxf(S[mi][2][r], S[mi][3][r]));
                t = fmaxf(t, __shfl_xor(t, 1, 16));
                t = fmaxf(t, __shfl_xor(t, 2, 16));
                t = fmaxf(t, __shfl_xor(t, 4, 16));
                t = fmaxf(t, __shfl_xor(t, 8, 16));
                if (r15 == 0) redA[wi][wm + mi * 16 + quad * 4 + r] = t;
            }
        __syncthreads();

        // ---- stats update, P -> LDS, partial row-sums ----
        #pragma unroll
        for (int mi = 0; mi < 4; ++mi)
            #pragma unroll
            for (int r = 0; r < 4; ++r) {
                const int row = wm + mi * 16 + quad * 4 + r;
                const float mnew = fmaxf(m_i[mi][r],
                                         fmaxf(redA[0][row], redA[1][row]));
                const float alpha = __expf(m_i[mi][r] - mnew);
                m_i[mi][r] = mnew;
                l_i[mi][r] *= alpha;
                float ps = 0.f;
                #pragma unroll
                for (int ni = 0; ni < 4; ++ni) {
                    const float pv = __expf(S[mi][ni][r] - mnew);
                    ps += pv;
                    Ps[row * PS_STRIDE + wn + ni * 16 + r15] = f2bf(pv);
                    Oacc[mi][ni][r] *= alpha;
                }
                ps += __shfl_xor(ps, 1, 16);
                ps += __shfl_xor(ps, 2, 16);
                ps += __shfl_xor(ps, 4, 16);
                ps += __shfl_xor(ps, 8, 16);
                if (r15 == 0) redB[wi][row] = ps;
            }
        __syncthreads();
        #pragma unroll
        for (int mi = 0; mi < 4; ++mi)
            #pragma unroll
            for (int r = 0; r < 4; ++r) {
                const int row = wm + mi * 16 + quad * 4 + r;
                l_i[mi][r] += redB[0][row] + redB[1][row];
            }

        // ---- O += P V over 4 t-chunks of 32 ----
        #pragma unroll
        for (int kst = 0; kst < 4; ++kst) {
            u16* buf = stage[kst & 1];
            async_cp16(Vtile + (long)sr0 * 2048 + kst * 32 + sc0, buf + tid * 8);
            async_cp16(Vtile + (long)sr1 * 2048 + kst * 32 + sc1, buf + (tid + 256) * 8);
            __syncthreads();
            bf16x8 af[4], bv[4];
            #pragma unroll
            for (int mi = 0; mi < 4; ++mi)
                af[mi] = *(const bf16x8*)&Ps[(wm + mi * 16 + r15) * PS_STRIDE
                                             + kst * 32 + quad * 8];
            #pragma unroll
            for (int ni = 0; ni < 4; ++ni)
                bv[ni] = *(const bf16x8*)&buf[(wn + ni * 16 + r15) * 32 + quad * 8];
            #pragma unroll
            for (int mi = 0; mi < 4; ++mi)
                #pragma unroll
                for (int ni = 0; ni < 4; ++ni)
                    Oacc[mi][ni] = __builtin_amdgcn_mfma_f32_16x16x32_bf16(
                        af[mi], bv[ni], Oacc[mi][ni], 0, 0, 0);
        }
        __syncthreads();
    }

    // ---- normalize + store ----
    #pragma unroll
    for (int mi = 0; mi < 4; ++mi)
        #pragma unroll
        for (int r = 0; r < 4; ++r) {
            const float inv = 1.f / l_i[mi][r];
            const long row = qrow0 + wm + mi * 16 + quad * 4 + r;
            #pragma unroll
            for (int ni = 0; ni < 4; ++ni)
                O[row * 2048 + h * 128 + wn + ni * 16 + r15] =
                    f2bf(Oacc[mi][ni][r] * inv);
        }
}

// ---------------------------------------------------------------------------
__global__ __launch_bounds__(256) void rmsnorm_kernel(
    const u16* __restrict__ x, const u16* __restrict__ w, u16* __restrict__ y, int n)
{
    const long row = blockIdx.x;
    const u16* xr = x + row * n;
    u16* yr = y + row * n;
    const int tid = threadIdx.x;
    const int cnt = n >> 8;
    float v[4];
    float ss = 0.f;
    for (int i = 0; i < cnt; ++i) { v[i] = bf2f(xr[tid + (i << 8)]); ss += v[i] * v[i]; }
    for (int o = 32; o; o >>= 1) ss += __shfl_xor(ss, o, 64);
    __shared__ float sm[4];
    if ((tid & 63) == 0) sm[tid >> 6] = ss;
    __syncthreads();
    const float rinv = rsqrtf((sm[0] + sm[1] + sm[2] + sm[3]) / (float)n + EPS);
    for (int i = 0; i < cnt; ++i) {
        const u16 nb = f2bf(v[i] * rinv);
        yr[tid + (i << 8)] = f2bf(bf2f(w[tid + (i << 8)]) * bf2f(nb));
    }
}

// kvf row (576) in place: rmsnorm(cols 0..511, w) ; rope(cols 512..575)
__global__ __launch_bounds__(256) void kv_kernel(
    const u16* __restrict__ cosb, const u16* __restrict__ sinb,
    const u16* __restrict__ w, u16* __restrict__ kvf)
{
    const long bs = blockIdx.x;
    const int s = (int)(bs & 2047);
    u16* io = kvf + bs * 576;
    const int tid = threadIdx.x;
    const float v0 = bf2f(io[tid * 2]), v1 = bf2f(io[tid * 2 + 1]);
    float ss = v0 * v0 + v1 * v1;
    for (int off = 32; off; off >>= 1) ss += __shfl_xor(ss, off, 64);
    __shared__ float sm[4];
    if ((tid & 63) == 0) sm[tid >> 6] = ss;
    __syncthreads();
    const float rinv = rsqrtf((sm[0] + sm[1] + sm[2] + sm[3]) / 512.f + EPS);
    const u16 n0 = f2bf(v0 * rinv), n1 = f2bf(v1 * rinv);
    io[tid * 2]     = f2bf(bf2f(w[tid * 2]) * bf2f(n0));
    io[tid * 2 + 1] = f2bf(bf2f(w[tid * 2 + 1]) * bf2f(n1));
    if (tid < 32) {
        const int j = tid;
        const float xr = bf2f(io[512 + 2 * j]), xi = bf2f(io[512 + 2 * j + 1]);
        const float c = bf2f(cosb[s * 32 + j]), si = bf2f(sinb[s * 32 + j]);
        io[512 + 2 * j]     = f2bf(bf2f(f2bf(xr * c))  - bf2f(f2bf(xi * si)));
        io[512 + 2 * j + 1] = f2bf(bf2f(f2bf(xr * si)) + bf2f(f2bf(xi * c)));
    }
}

// in-place rope on q's pe columns (h*192+128 .. +191)
__global__ __launch_bounds__(256) void rope_q_kernel(
    const u16* __restrict__ cosb, const u16* __restrict__ sinb, u16* __restrict__ q)
{
    const int idx = blockIdx.x * 256 + threadIdx.x; // 4096*16*32
    const int j = idx & 31;
    const int h = (idx >> 5) & 15;
    const int bs = idx >> 9;
    const int s = bs & 2047;
    u16* p = q + (long)bs * 3072 + h * 192 + 128 + 2 * j;
    const float xr = bf2f(p[0]), xi = bf2f(p[1]);
    const float c = bf2f(cosb[s * 32 + j]), si = bf2f(sinb[s * 32 + j]);
    p[0] = f2bf(bf2f(f2bf(xr * c))  - bf2f(f2bf(xi * si)));
    p[1] = f2bf(bf2f(f2bf(xr * si)) + bf2f(f2bf(xi * c)));
}

// broadcast roped k_pe (kvf cols 512..575) into K2 cols h*192+128..+191
__global__ __launch_bounds__(256) void k2rope_kernel(
    const u16* __restrict__ kvf, u16* __restrict__ K2)
{
    const long row = blockIdx.x;
    const int tid = threadIdx.x;
    #pragma unroll
    for (int i = 0; i < 4; ++i) {
        const int slot = tid + (i << 8);      // 0..1023 = 16h x 64r
        const int h = slot >> 6, r = slot & 63;
        K2[row * 3072 + h * 192 + 128 + r] = kvf[row * 576 + 512 + r];
    }
}

// ---------------------------------------------------------------------------
extern "C" void kernel_launch(void* const* d_in, const int* in_sizes, int n_in,
                              void* d_out, int out_size, void* d_ws, size_t ws_size,
                              hipStream_t stream)
{
    float* out = (float*)d_out;   // fp32 output per reference dtype

    // -------- bf16 arena layout in d_ws --------
    char* p = (char*)d_ws;
    auto alloc = [&](size_t elems) { u16* r = (u16*)p; p += elems * 2; return r; };
    u16* c_cos  = alloc(65536);
    u16* c_sin  = alloc(65536);
    u16* c_wqa  = alloc(2097152);
    u16* c_wqab = alloc(1024);
    u16* c_qnw  = alloc(1024);
    u16* c_wqb  = alloc(3145728);
    u16* c_wqbb = alloc(3072);
    u16* c_wkva = alloc(1179648);
    u16* c_wkvab= alloc(576);
    u16* c_kvnw = alloc(512);
    u16* c_wkvb = alloc(2097152);
    u16* c_wo   = alloc(4194304);
    u16* c_wob  = alloc(2048);
    // intermediates
    u16* q   = alloc(4096UL * 3072);          // 25.2 MB
    u16* kvf = alloc(4096UL * 576);           //  4.7 MB
    u16* K2  = alloc(4096UL * 3072);          // 25.2 MB
    u16* O   = alloc(4096UL * 2048);          // 16.8 MB
    u16* q_a = (u16*)p;                       //  8.4 MB (tail)
    // d_out scratch: x_bf16 lower half (dead after step 4), Vt upper half
    u16* xb = (u16*)d_out;
    u16* Vt = (u16*)d_out + 8388608;

    // -------- conversion --------
    Cvt cv;
    const long sizes[14] = {8388608, 65536, 65536, 2097152, 1024, 1024, 3145728,
                            3072, 1179648, 576, 512, 2097152, 4194304, 2048};
    u16* dsts[14] = {xb, c_cos, c_sin, c_wqa, c_wqab, c_qnw, c_wqb, c_wqbb,
                     c_wkva, c_wkvab, c_kvnw, c_wkvb, c_wo, c_wob};
    const int srcidx[14] = {0, 2, 3, 4, 5, 6, 7, 8, 9, 10, 11, 12, 13, 14};
    long acc_off = 0;
    for (int t = 0; t < 14; ++t) {
        cv.src[t] = d_in[srcidx[t]];
        cv.dst[t] = dsts[t];
        cv.off[t] = acc_off;
        acc_off += sizes[t];
    }
    cv.off[14] = acc_off;
    const long total8 = acc_off / 8;
    cvt_kernel<<<dim3((unsigned)((total8 + 255) / 256)), dim3(256), 0, stream>>>(
        cv, (const uint32_t*)d_in[6], total8);

    auto gemm = [&](const u16* A, const u16* B, const u16* bias, u16* C,
                    int M, int N, int K, int lda, int ldb, int ldc, float alpha,
                    int c_f32, int nz, int z0, int hcnt,
                    long sAl, long sAb, long sAh,
                    long sBl, long sBb, long sBh,
                    long sCl, long sCb, long sCh) {
        dim3 grid((N + 127) / 128, M / 128, nz);
        gemm_bt_kernel<<<grid, dim3(256), 0, stream>>>(
            A, B, bias, C, M, N, K, lda, ldb, ldc, alpha, c_f32, z0, hcnt,
            sAl, sAb, sAh, sBl, sBb, sBh, sCl, sCb, sCh);
    };

    // 1) q_a = x @ wq_a^T + b
    gemm(xb, c_wqa, c_wqab, q_a, 4096, 1024, 2048, 2048, 2048, 1024, 1.f, 0,
         1, 0, 1, 0, 0, 0, 0, 0, 0, 0, 0, 0);
    // 2) rmsnorm in place
    rmsnorm_kernel<<<4096, 256, 0, stream>>>(q_a, c_qnw, q_a, 1024);
    // 3) q = q_a @ wq_b^T + b
    gemm(q_a, c_wqb, c_wqbb, q, 4096, 3072, 1024, 1024, 1024, 3072, 1.f, 0,
         1, 0, 1, 0, 0, 0, 0, 0, 0, 0, 0, 0);
    // 4) kvf = x @ wkv_a^T + b   (last read of xb)
    gemm(xb, c_wkva, c_wkvab, kvf, 4096, 576, 2048, 2048, 2048, 576, 1.f, 0,
         1, 0, 1, 0, 0, 0, 0, 0, 0, 0, 0, 0);
    // 5) kvf in place: norm(0..511) + rope(512..575)
    kv_kernel<<<4096, 256, 0, stream>>>(c_cos, c_sin, c_kvnw, kvf);
    // 6) rope q_pe in place
    rope_q_kernel<<<8192, 256, 0, stream>>>(c_cos, c_sin, q);
    // 7) K2 nope: per head, k_nope[t][d] = kv_c[t] . wkvb[h][d]
    gemm(kvf, c_wkvb, nullptr, K2, 4096, 128, 512, 576, 512, 3072, 1.f, 0,
         16, 0, 16, 0, 0, 0, 0, 0, 256L * 512, 0, 0, 192);
    // 8) K2 rope broadcast
    k2rope_kernel<<<4096, 256, 0, stream>>>(kvf, K2);
    // 9) Vt[b][h][d][t] = wkvb_v[h][d] . kv_c[b][t]  (into d_out upper half)
    gemm(c_wkvb + 128 * 512, kvf, nullptr, Vt, 128, 2048, 512, 512, 576, 2048, 1.f, 0,
         32, 0, 16,
         0, 0, 256L * 512,
         0, 2048L * 576, 0,
         0, 16L * 128 * 2048, 128L * 2048);
    // 10) flash attention: q,K2,Vt -> O
    flash_kernel<<<dim3(16, 32), dim3(256), 0, stream>>>(q, K2, Vt, O);
    // 11) out = O @ wo^T + b  (fp32 store; overwrites all of d_out)
    gemm(O, c_wo, c_wob, (u16*)out, 4096, 2048, 2048, 2048, 2048, 2048, 1.f, 1,
         1, 0, 1, 0, 0, 0, 0, 0, 0, 0, 0, 0);
}

// Round 5
// 747.887 us; speedup vs baseline: 1.1263x; 1.0667x over previous
//
#include <hip/hip_runtime.h>
#include <stdint.h>

typedef uint16_t u16;
typedef __bf16 bf16x8 __attribute__((ext_vector_type(8)));
typedef float f32x4 __attribute__((ext_vector_type(4)));

#define EPS 1e-3f
#define SCALE_F 0.07216878364870323f /* 192^-0.5 */

__device__ __forceinline__ float bf2f(u16 u) {
    union { uint32_t i; float f; } v; v.i = ((uint32_t)u) << 16; return v.f;
}
__device__ __forceinline__ u16 f2bf(float f) {
    union { float f; uint32_t i; } v; v.f = f;
    uint32_t x = v.i;
    return (u16)((x + 0x7fffu + ((x >> 16) & 1u)) >> 16);
}

__device__ __forceinline__ void async_cp16(const u16* g, u16* l) {
    __builtin_amdgcn_global_load_lds(
        (const __attribute__((address_space(1))) uint32_t*)g,
        (__attribute__((address_space(3))) uint32_t*)l,
        16, 0, 0);
}

// ---------------------------------------------------------------------------
// dtype-adaptive input conversion: all 14 float tensors -> bf16 arena.
// fp32 detected via q_norm_w[0] bit pattern (all-ones tensor).
// ---------------------------------------------------------------------------
struct Cvt {
    const void* src[14];
    u16* dst[14];
    long off[15];
};

__global__ __launch_bounds__(256) void cvt_kernel(Cvt c, const uint32_t* qnw_u32, long total8)
{
    const long i8 = (long)blockIdx.x * 256 + threadIdx.x;
    if (i8 >= total8) return;
    const long e = i8 * 8;
    const bool is_f32 = (qnw_u32[0] == 0x3F800000u);
    int t = 0;
    while (e >= c.off[t + 1]) ++t;          // all segment sizes are multiples of 8
    const long local = e - c.off[t];
    u16* d = c.dst[t] + local;
    if (is_f32) {
        const float* s = (const float*)c.src[t] + local;
        #pragma unroll
        for (int j = 0; j < 8; ++j) d[j] = f2bf(s[j]);
    } else {
        const u16* s = (const u16*)c.src[t] + local;
        #pragma unroll
        for (int j = 0; j < 8; ++j) d[j] = s[j];
    }
}

// ---------------------------------------------------------------------------
// Generic bf16 GEMM: C[M,N] = rnd(rnd(alpha*acc) + bias), acc = A[M,K]@B[N,K]^T
// z-batched; B rows clamped; M%128==0, K%32==0. c_f32: fp32 store.
// ---------------------------------------------------------------------------
__global__ __launch_bounds__(256) void gemm_bt_kernel(
    const u16* __restrict__ A, const u16* __restrict__ B,
    const u16* __restrict__ bias, u16* __restrict__ C,
    int M, int N, int K, int lda, int ldb, int ldc, float alpha, int c_f32,
    int z0, int hcnt,
    long sAl, long sAb, long sAh,
    long sBl, long sBb, long sBh,
    long sCl, long sCb, long sCh)
{
    const int zl = blockIdx.z;
    const int zg = z0 + zl;
    const int zb = zg / hcnt, zh = zg - zb * hcnt;
    A += (long)zl * sAl + (long)zb * sAb + (long)zh * sAh;
    B += (long)zl * sBl + (long)zb * sBb + (long)zh * sBh;
    C += (long)zl * sCl + (long)zb * sCb + (long)zh * sCh;

    __shared__ u16 As[128 * 32];
    __shared__ u16 Bs[128 * 32];

    const int tid  = threadIdx.x;
    const int wave = tid >> 6, lane = tid & 63;
    const int wm = (wave >> 1) << 6, wn = (wave & 1) << 6;
    const int quad = lane >> 4, r15 = lane & 15;

    const int tileM = blockIdx.y * 128;
    const int tileN = blockIdx.x * 128;

    const int c0 = tid, c1 = tid + 256;
    const int rA0 = c0 >> 2, kb0 = (c0 & 3) << 3;
    const int rA1 = c1 >> 2, kb1 = (c1 & 3) << 3;
    int rB0 = tileN + rA0; if (rB0 > N - 1) rB0 = N - 1;
    int rB1 = tileN + rA1; if (rB1 > N - 1) rB1 = N - 1;

    const u16* Ag0 = A + (long)(tileM + rA0) * lda + kb0;
    const u16* Ag1 = A + (long)(tileM + rA1) * lda + kb1;
    const u16* Bg0 = B + (long)rB0 * ldb + kb0;
    const u16* Bg1 = B + (long)rB1 * ldb + kb1;
    u16* lA0 = &As[c0 << 3];
    u16* lA1 = &As[c1 << 3];
    u16* lB0 = &Bs[c0 << 3];
    u16* lB1 = &Bs[c1 << 3];

    f32x4 acc[4][4] = {};

    const u16* aRd[4]; const u16* bRd[4];
    #pragma unroll
    for (int i = 0; i < 4; ++i) {
        aRd[i] = &As[(wm + i * 16 + r15) * 32 + quad * 8];
        bRd[i] = &Bs[(wn + i * 16 + r15) * 32 + quad * 8];
    }

    for (int k0 = 0; k0 < K; k0 += 32) {
        async_cp16(Ag0, lA0);
        async_cp16(Ag1, lA1);
        async_cp16(Bg0, lB0);
        async_cp16(Bg1, lB1);
        Ag0 += 32; Ag1 += 32; Bg0 += 32; Bg1 += 32;
        __syncthreads();
        bf16x8 af[4], bfr[4];
        #pragma unroll
        for (int i = 0; i < 4; ++i) {
            af[i]  = *(const bf16x8*)aRd[i];
            bfr[i] = *(const bf16x8*)bRd[i];
        }
        #pragma unroll
        for (int mi = 0; mi < 4; ++mi)
            #pragma unroll
            for (int ni = 0; ni < 4; ++ni)
                acc[mi][ni] = __builtin_amdgcn_mfma_f32_16x16x32_bf16(
                    af[mi], bfr[ni], acc[mi][ni], 0, 0, 0);
        __syncthreads();
    }

    #pragma unroll
    for (int mi = 0; mi < 4; ++mi) {
        const int row = tileM + wm + mi * 16 + quad * 4;
        #pragma unroll
        for (int ni = 0; ni < 4; ++ni) {
            const int col = tileN + wn + ni * 16 + r15;
            if (col < N) {
                if (c_f32) {
                    const float bv = bias ? bf2f(bias[col]) : 0.f;
                    #pragma unroll
                    for (int r = 0; r < 4; ++r)
                        ((float*)C)[(long)(row + r) * ldc + col] =
                            acc[mi][ni][r] * alpha + bv;
                } else {
                    #pragma unroll
                    for (int r = 0; r < 4; ++r) {
                        u16 t = f2bf(acc[mi][ni][r] * alpha);
                        if (bias) t = f2bf(bf2f(t) + bf2f(bias[col]));
                        C[(long)(row + r) * ldc + col] = t;
                    }
                }
            }
        }
    }
}

// ---------------------------------------------------------------------------
// Zero-barrier flash attention.
// Block = 128 q-rows x one (b,h). Wave w owns rows w*32..w*32+31 (full 128
// k-cols) -> softmax stats are wave-local. K and V fragments are loaded
// global->VGPR directly (no LDS staging). P's C->A layout transform goes
// through a per-wave private LDS strip (lgkmcnt only, no __syncthreads).
// ---------------------------------------------------------------------------
#define PS 136   /* u16 stride; 136*2=272 keeps 16B alignment per row */

__global__ __launch_bounds__(256, 2) void flash_kernel(
    const u16* __restrict__ q, const u16* __restrict__ K2,
    const u16* __restrict__ Vt, u16* __restrict__ O)
{
    __shared__ u16 Ps[4][32 * PS];

    const int mt = blockIdx.x, bh = blockIdx.y;
    const int b = bh >> 4, h = bh & 15;
    const int tid = threadIdx.x;
    const int wave = tid >> 6, lane = tid & 63;
    const int quad = lane >> 4, r15 = lane & 15;

    const long qrow0 = (long)b * 2048 + mt * 128 + wave * 32;
    u16* myPs = Ps[wave];

    // preload Q fragments (A-layout): rows qrow0 + mi*16 + r15
    bf16x8 qf[2][6];
    #pragma unroll
    for (int mi = 0; mi < 2; ++mi) {
        const u16* qp = q + (qrow0 + mi * 16 + r15) * 3072 + h * 192 + quad * 8;
        #pragma unroll
        for (int kst = 0; kst < 6; ++kst)
            qf[mi][kst] = *(const bf16x8*)(qp + kst * 32);
    }

    f32x4 Oacc[2][8] = {};
    float m_i[2][4], l_i[2][4];
    #pragma unroll
    for (int mi = 0; mi < 2; ++mi)
        #pragma unroll
        for (int r = 0; r < 4; ++r) { m_i[mi][r] = -1e30f; l_i[mi][r] = 0.f; }

    const u16* Kbh = K2 + (long)b * 2048 * 3072 + h * 192;
    const u16* Vbh = Vt + (long)bh * 128 * 2048;

    for (int j = 0; j < 16; ++j) {
        const u16* Kt = Kbh + (long)j * 128 * 3072;

        // ---- S = Q K^T : direct global B-fragment loads, no barriers ----
        f32x4 S[2][8] = {};
        #pragma unroll
        for (int kst = 0; kst < 6; ++kst) {
            bf16x8 bfr[8];
            #pragma unroll
            for (int ni = 0; ni < 8; ++ni)
                bfr[ni] = *(const bf16x8*)(Kt + (long)(ni * 16 + r15) * 3072
                                           + kst * 32 + quad * 8);
            #pragma unroll
            for (int mi = 0; mi < 2; ++mi)
                #pragma unroll
                for (int ni = 0; ni < 8; ++ni)
                    S[mi][ni] = __builtin_amdgcn_mfma_f32_16x16x32_bf16(
                        qf[mi][kst], bfr[ni], S[mi][ni], 0, 0, 0);
        }
        #pragma unroll
        for (int mi = 0; mi < 2; ++mi)
            #pragma unroll
            for (int ni = 0; ni < 8; ++ni)
                #pragma unroll
                for (int r = 0; r < 4; ++r)
                    S[mi][ni][r] *= SCALE_F;

        // ---- wave-local online softmax (rows mi*16+quad*4+r) ----
        #pragma unroll
        for (int mi = 0; mi < 2; ++mi)
            #pragma unroll
            for (int r = 0; r < 4; ++r) {
                float t = S[mi][0][r];
                #pragma unroll
                for (int ni = 1; ni < 8; ++ni) t = fmaxf(t, S[mi][ni][r]);
                t = fmaxf(t, __shfl_xor(t, 1, 16));
                t = fmaxf(t, __shfl_xor(t, 2, 16));
                t = fmaxf(t, __shfl_xor(t, 4, 16));
                t = fmaxf(t, __shfl_xor(t, 8, 16));
                const float mnew = fmaxf(m_i[mi][r], t);
                const float al = __expf(m_i[mi][r] - mnew);
                m_i[mi][r] = mnew;
                const int lrow = mi * 16 + quad * 4 + r;
                float ps = 0.f;
                #pragma unroll
                for (int ni = 0; ni < 8; ++ni) {
                    const float pv = __expf(S[mi][ni][r] - mnew);
                    ps += pv;
                    myPs[lrow * PS + ni * 16 + r15] = f2bf(pv);
                    Oacc[mi][ni][r] *= al;
                }
                ps += __shfl_xor(ps, 1, 16);
                ps += __shfl_xor(ps, 2, 16);
                ps += __shfl_xor(ps, 4, 16);
                ps += __shfl_xor(ps, 8, 16);
                l_i[mi][r] = l_i[mi][r] * al + ps;
            }

        // ---- O += P V : P from private LDS strip, V direct from global ----
        const u16* Vtile = Vbh + j * 128;
        #pragma unroll
        for (int kst = 0; kst < 4; ++kst) {
            bf16x8 af[2], bv[8];
            #pragma unroll
            for (int mi = 0; mi < 2; ++mi)
                af[mi] = *(const bf16x8*)&myPs[(mi * 16 + r15) * PS
                                               + kst * 32 + quad * 8];
            #pragma unroll
            for (int ni = 0; ni < 8; ++ni)
                bv[ni] = *(const bf16x8*)(Vtile + (long)(ni * 16 + r15) * 2048
                                          + kst * 32 + quad * 8);
            #pragma unroll
            for (int mi = 0; mi < 2; ++mi)
                #pragma unroll
                for (int ni = 0; ni < 8; ++ni)
                    Oacc[mi][ni] = __builtin_amdgcn_mfma_f32_16x16x32_bf16(
                        af[mi], bv[ni], Oacc[mi][ni], 0, 0, 0);
        }
    }

    // ---- normalize + store ----
    #pragma unroll
    for (int mi = 0; mi < 2; ++mi)
        #pragma unroll
        for (int r = 0; r < 4; ++r) {
            const float inv = 1.f / l_i[mi][r];
            const long row = qrow0 + mi * 16 + quad * 4 + r;
            #pragma unroll
            for (int ni = 0; ni < 8; ++ni)
                O[row * 2048 + h * 128 + ni * 16 + r15] =
                    f2bf(Oacc[mi][ni][r] * inv);
        }
}

// ---------------------------------------------------------------------------
__global__ __launch_bounds__(256) void rmsnorm_kernel(
    const u16* __restrict__ x, const u16* __restrict__ w, u16* __restrict__ y, int n)
{
    const long row = blockIdx.x;
    const u16* xr = x + row * n;
    u16* yr = y + row * n;
    const int tid = threadIdx.x;
    const int cnt = n >> 8;
    float v[4];
    float ss = 0.f;
    for (int i = 0; i < cnt; ++i) { v[i] = bf2f(xr[tid + (i << 8)]); ss += v[i] * v[i]; }
    for (int o = 32; o; o >>= 1) ss += __shfl_xor(ss, o, 64);
    __shared__ float sm[4];
    if ((tid & 63) == 0) sm[tid >> 6] = ss;
    __syncthreads();
    const float rinv = rsqrtf((sm[0] + sm[1] + sm[2] + sm[3]) / (float)n + EPS);
    for (int i = 0; i < cnt; ++i) {
        const u16 nb = f2bf(v[i] * rinv);
        yr[tid + (i << 8)] = f2bf(bf2f(w[tid + (i << 8)]) * bf2f(nb));
    }
}

// kvf row (576) in place: rmsnorm(cols 0..511, w) ; rope(cols 512..575)
__global__ __launch_bounds__(256) void kv_kernel(
    const u16* __restrict__ cosb, const u16* __restrict__ sinb,
    const u16* __restrict__ w, u16* __restrict__ kvf)
{
    const long bs = blockIdx.x;
    const int s = (int)(bs & 2047);
    u16* io = kvf + bs * 576;
    const int tid = threadIdx.x;
    const float v0 = bf2f(io[tid * 2]), v1 = bf2f(io[tid * 2 + 1]);
    float ss = v0 * v0 + v1 * v1;
    for (int off = 32; off; off >>= 1) ss += __shfl_xor(ss, off, 64);
    __shared__ float sm[4];
    if ((tid & 63) == 0) sm[tid >> 6] = ss;
    __syncthreads();
    const float rinv = rsqrtf((sm[0] + sm[1] + sm[2] + sm[3]) / 512.f + EPS);
    const u16 n0 = f2bf(v0 * rinv), n1 = f2bf(v1 * rinv);
    io[tid * 2]     = f2bf(bf2f(w[tid * 2]) * bf2f(n0));
    io[tid * 2 + 1] = f2bf(bf2f(w[tid * 2 + 1]) * bf2f(n1));
    if (tid < 32) {
        const int j = tid;
        const float xr = bf2f(io[512 + 2 * j]), xi = bf2f(io[512 + 2 * j + 1]);
        const float c = bf2f(cosb[s * 32 + j]), si = bf2f(sinb[s * 32 + j]);
        io[512 + 2 * j]     = f2bf(bf2f(f2bf(xr * c))  - bf2f(f2bf(xi * si)));
        io[512 + 2 * j + 1] = f2bf(bf2f(f2bf(xr * si)) + bf2f(f2bf(xi * c)));
    }
}

// in-place rope on q's pe columns (h*192+128 .. +191)
__global__ __launch_bounds__(256) void rope_q_kernel(
    const u16* __restrict__ cosb, const u16* __restrict__ sinb, u16* __restrict__ q)
{
    const int idx = blockIdx.x * 256 + threadIdx.x; // 4096*16*32
    const int j = idx & 31;
    const int h = (idx >> 5) & 15;
    const int bs = idx >> 9;
    const int s = bs & 2047;
    u16* p = q + (long)bs * 3072 + h * 192 + 128 + 2 * j;
    const float xr = bf2f(p[0]), xi = bf2f(p[1]);
    const float c = bf2f(cosb[s * 32 + j]), si = bf2f(sinb[s * 32 + j]);
    p[0] = f2bf(bf2f(f2bf(xr * c))  - bf2f(f2bf(xi * si)));
    p[1] = f2bf(bf2f(f2bf(xr * si)) + bf2f(f2bf(xi * c)));
}

// broadcast roped k_pe (kvf cols 512..575) into K2 cols h*192+128..+191
__global__ __launch_bounds__(256) void k2rope_kernel(
    const u16* __restrict__ kvf, u16* __restrict__ K2)
{
    const long row = blockIdx.x;
    const int tid = threadIdx.x;
    #pragma unroll
    for (int i = 0; i < 4; ++i) {
        const int slot = tid + (i << 8);      // 0..1023 = 16h x 64r
        const int h = slot >> 6, r = slot & 63;
        K2[row * 3072 + h * 192 + 128 + r] = kvf[row * 576 + 512 + r];
    }
}

// ---------------------------------------------------------------------------
extern "C" void kernel_launch(void* const* d_in, const int* in_sizes, int n_in,
                              void* d_out, int out_size, void* d_ws, size_t ws_size,
                              hipStream_t stream)
{
    float* out = (float*)d_out;   // fp32 output per reference dtype

    // -------- bf16 arena layout in d_ws --------
    char* p = (char*)d_ws;
    auto alloc = [&](size_t elems) { u16* r = (u16*)p; p += elems * 2; return r; };
    u16* c_cos  = alloc(65536);
    u16* c_sin  = alloc(65536);
    u16* c_wqa  = alloc(2097152);
    u16* c_wqab = alloc(1024);
    u16* c_qnw  = alloc(1024);
    u16* c_wqb  = alloc(3145728);
    u16* c_wqbb = alloc(3072);
    u16* c_wkva = alloc(1179648);
    u16* c_wkvab= alloc(576);
    u16* c_kvnw = alloc(512);
    u16* c_wkvb = alloc(2097152);
    u16* c_wo   = alloc(4194304);
    u16* c_wob  = alloc(2048);
    // intermediates
    u16* q   = alloc(4096UL * 3072);          // 25.2 MB
    u16* kvf = alloc(4096UL * 576);           //  4.7 MB
    u16* K2  = alloc(4096UL * 3072);          // 25.2 MB
    u16* O   = alloc(4096UL * 2048);          // 16.8 MB
    u16* q_a = (u16*)p;                       //  8.4 MB (tail)
    // d_out scratch: x_bf16 lower half (dead after step 4), Vt upper half
    u16* xb = (u16*)d_out;
    u16* Vt = (u16*)d_out + 8388608;

    // -------- conversion --------
    Cvt cv;
    const long sizes[14] = {8388608, 65536, 65536, 2097152, 1024, 1024, 3145728,
                            3072, 1179648, 576, 512, 2097152, 4194304, 2048};
    u16* dsts[14] = {xb, c_cos, c_sin, c_wqa, c_wqab, c_qnw, c_wqb, c_wqbb,
                     c_wkva, c_wkvab, c_kvnw, c_wkvb, c_wo, c_wob};
    const int srcidx[14] = {0, 2, 3, 4, 5, 6, 7, 8, 9, 10, 11, 12, 13, 14};
    long acc_off = 0;
    for (int t = 0; t < 14; ++t) {
        cv.src[t] = d_in[srcidx[t]];
        cv.dst[t] = dsts[t];
        cv.off[t] = acc_off;
        acc_off += sizes[t];
    }
    cv.off[14] = acc_off;
    const long total8 = acc_off / 8;
    cvt_kernel<<<dim3((unsigned)((total8 + 255) / 256)), dim3(256), 0, stream>>>(
        cv, (const uint32_t*)d_in[6], total8);

    auto gemm = [&](const u16* A, const u16* B, const u16* bias, u16* C,
                    int M, int N, int K, int lda, int ldb, int ldc, float alpha,
                    int c_f32, int nz, int z0, int hcnt,
                    long sAl, long sAb, long sAh,
                    long sBl, long sBb, long sBh,
                    long sCl, long sCb, long sCh) {
        dim3 grid((N + 127) / 128, M / 128, nz);
        gemm_bt_kernel<<<grid, dim3(256), 0, stream>>>(
            A, B, bias, C, M, N, K, lda, ldb, ldc, alpha, c_f32, z0, hcnt,
            sAl, sAb, sAh, sBl, sBb, sBh, sCl, sCb, sCh);
    };

    // 1) q_a = x @ wq_a^T + b
    gemm(xb, c_wqa, c_wqab, q_a, 4096, 1024, 2048, 2048, 2048, 1024, 1.f, 0,
         1, 0, 1, 0, 0, 0, 0, 0, 0, 0, 0, 0);
    // 2) rmsnorm in place
    rmsnorm_kernel<<<4096, 256, 0, stream>>>(q_a, c_qnw, q_a, 1024);
    // 3) q = q_a @ wq_b^T + b
    gemm(q_a, c_wqb, c_wqbb, q, 4096, 3072, 1024, 1024, 1024, 3072, 1.f, 0,
         1, 0, 1, 0, 0, 0, 0, 0, 0, 0, 0, 0);
    // 4) kvf = x @ wkv_a^T + b   (last read of xb)
    gemm(xb, c_wkva, c_wkvab, kvf, 4096, 576, 2048, 2048, 2048, 576, 1.f, 0,
         1, 0, 1, 0, 0, 0, 0, 0, 0, 0, 0, 0);
    // 5) kvf in place: norm(0..511) + rope(512..575)
    kv_kernel<<<4096, 256, 0, stream>>>(c_cos, c_sin, c_kvnw, kvf);
    // 6) rope q_pe in place
    rope_q_kernel<<<8192, 256, 0, stream>>>(c_cos, c_sin, q);
    // 7) K2 nope: per head, k_nope[t][d] = kv_c[t] . wkvb[h][d]
    gemm(kvf, c_wkvb, nullptr, K2, 4096, 128, 512, 576, 512, 3072, 1.f, 0,
         16, 0, 16, 0, 0, 0, 0, 0, 256L * 512, 0, 0, 192);
    // 8) K2 rope broadcast
    k2rope_kernel<<<4096, 256, 0, stream>>>(kvf, K2);
    // 9) Vt[b][h][d][t] = wkvb_v[h][d] . kv_c[b][t]  (into d_out upper half)
    gemm(c_wkvb + 128 * 512, kvf, nullptr, Vt, 128, 2048, 512, 512, 576, 2048, 1.f, 0,
         32, 0, 16,
         0, 0, 256L * 512,
         0, 2048L * 576, 0,
         0, 16L * 128 * 2048, 128L * 2048);
    // 10) zero-barrier flash attention: q,K2,Vt -> O
    flash_kernel<<<dim3(16, 32), dim3(256), 0, stream>>>(q, K2, Vt, O);
    // 11) out = O @ wo^T + b  (fp32 store; overwrites all of d_out)
    gemm(O, c_wo, c_wob, (u16*)out, 4096, 2048, 2048, 2048, 2048, 2048, 1.f, 1,
         1, 0, 1, 0, 0, 0, 0, 0, 0, 0, 0, 0);
}